// Round 10
// baseline (223.544 us; speedup 1.0000x reference)
//
#include <hip/hip_runtime.h>

#define HW 65536
#define NBATCH 16
#define CCH 64
#define QKC 32

// workspace layout (float offsets)
#define OFF_WQT 0        // [64][32]  WqT folded (c-major rows of 32)
#define OFF_BQ  2048     // [32]
#define OFF_WKT 2080     // [64][32]
#define OFF_BK  4128     // [32]
#define OFF_WVT 4160     // [64][64]
#define OFF_BV  8256     // [64]
#define OFF_WO  8320     // [64][64]  row-major [c][j]
#define OFF_BO  12416    // [64]
#define OFF_F   12544    // [16][32][64]
#define OFF_MT  45312    // [16][32][64]

#define BPN_A 128
#define BPN_B 128
#define CHUNK_PX 128
#define SP 129           // LDS channel stride in floats: odd -> <=2-way frag-read conflicts
#define NIT_A (HW / CHUNK_PX / BPN_A)   // 4 chunks (contiguous 512-px span) per block
#define NIT_B (HW / CHUNK_PX / BPN_B)   // 4

typedef __attribute__((ext_vector_type(4))) float f32x4;
typedef __attribute__((ext_vector_type(8))) short bf16x8;
typedef __attribute__((ext_vector_type(4))) short bf16x4;

#define MFMA_P(a, b, c) __builtin_amdgcn_mfma_f32_16x16x32_bf16(a, b, c, 0, 0, 0)
#define MFMA_O(a, b, c) __builtin_amdgcn_mfma_f32_16x16x16bf16_1k(a, b, c, 0, 0, 0)

// LDS-only barrier: drain LDS ops but leave prefetch global loads in flight
// (__syncthreads would emit s_waitcnt vmcnt(0) and expose HBM latency).
#define LDS_BARRIER()                                          \
    do {                                                       \
        asm volatile("s_waitcnt lgkmcnt(0)" ::: "memory");     \
        __builtin_amdgcn_s_barrier();                          \
    } while (0)

// float -> bf16 via hardware cvt (m240: plain cast compiles to the HW instr)
__device__ __forceinline__ short f2bf(float f) {
    __bf16 h = (__bf16)f;
    return __builtin_bit_cast(short, h);
}

__global__ __launch_bounds__(256) void k0_fold(
    const float* __restrict__ Wq, const float* __restrict__ bq,
    const float* __restrict__ qg, const float* __restrict__ qb,
    const float* __restrict__ qm, const float* __restrict__ qv,
    const float* __restrict__ Wk, const float* __restrict__ bk,
    const float* __restrict__ kg, const float* __restrict__ kb,
    const float* __restrict__ km, const float* __restrict__ kvar,
    const float* __restrict__ Wv, const float* __restrict__ bv,
    const float* __restrict__ vg, const float* __restrict__ vb,
    const float* __restrict__ vm, const float* __restrict__ vvar,
    const float* __restrict__ Wo, const float* __restrict__ bo,
    const float* __restrict__ og, const float* __restrict__ ob,
    const float* __restrict__ om, const float* __restrict__ ovar,
    float* __restrict__ ws)
{
    const int idx = blockIdx.x * 256 + threadIdx.x;
    if (idx < 2048) {                       // WqT[c][i]
        const int c = idx >> 5, i = idx & 31;
        const float s = qg[i] * rsqrtf(qv[i] + 1e-5f);
        ws[OFF_WQT + idx] = Wq[i * 64 + c] * s;
    } else if (idx < 2080) {
        const int i = idx - 2048;
        const float s = qg[i] * rsqrtf(qv[i] + 1e-5f);
        ws[OFF_BQ + i] = bq[i] * s + qb[i] - qm[i] * s;
    } else if (idx < 4128) {                // WkT[c][i]
        const int t = idx - 2080;
        const int c = t >> 5, i = t & 31;
        const float s = kg[i] * rsqrtf(kvar[i] + 1e-5f);
        ws[OFF_WKT + t] = Wk[i * 64 + c] * s;
    } else if (idx < 4160) {
        const int i = idx - 4128;
        const float s = kg[i] * rsqrtf(kvar[i] + 1e-5f);
        ws[OFF_BK + i] = bk[i] * s + kb[i] - km[i] * s;
    } else if (idx < 8256) {                // WvT[c][o]
        const int t = idx - 4160;
        const int c = t >> 6, o = t & 63;
        const float s = vg[o] * rsqrtf(vvar[o] + 1e-5f);
        ws[OFF_WVT + t] = Wv[o * 64 + c] * s;
    } else if (idx < 8320) {
        const int o = idx - 8256;
        const float s = vg[o] * rsqrtf(vvar[o] + 1e-5f);
        ws[OFF_BV + o] = bv[o] * s + vb[o] - vm[o] * s;
    } else if (idx < 12416) {               // Wo'[c][j]
        const int t = idx - 8320;
        const int c = t >> 6, j = t & 63;
        const float s = og[c] * rsqrtf(ovar[c] + 1e-5f);
        ws[OFF_WO + t] = Wo[c * 64 + j] * s;
    } else if (idx < 12480) {
        const int c = idx - 12416;
        const float s = og[c] * rsqrtf(ovar[c] + 1e-5f);
        ws[OFF_BO + c] = bo[c] * s + ob[c] - om[c] * s;
    } else if (idx < 12480 + 32768) {       // zero F (must happen every launch)
        ws[OFF_F + (idx - 12480)] = 0.0f;
    }
}

// Pass A: streaming loads. Per 128-px chunk the block loads x CONTIGUOUSLY
// (each wave instr = 512B-per-channel runs), stages into LDS [64][SP], then
// waves ds_read their MFMA fragments. gloads for the next chunk stay in
// flight across the LDS barrier (LDS_BARRIER does not drain vmcnt).
__global__ __launch_bounds__(256) void k1_passA(const float* __restrict__ x,
                                                const float* __restrict__ wsc,
                                                float* __restrict__ f)
{
    __shared__ float lds[64 * SP];   // x-tile; reused as red[4*2048] in epilogue

    const int tid = threadIdx.x;
    const int w = tid >> 6;
    const int lane = tid & 63;
    const int ln = lane & 15;
    const int lg = lane >> 4;
    const int lc = tid >> 5;          // loader: channel sub-index (0..7)
    const int lpx = (tid & 31) * 4;   // loader: px offset (0..124)

    const int n = blockIdx.x / BPN_A;
    const int bslot = blockIdx.x % BPN_A;
    const float* xn = x + (size_t)n * CCH * HW;

    bf16x8 wkf[2][2];
#pragma unroll
    for (int kk = 0; kk < 2; kk++)
#pragma unroll
        for (int t = 0; t < 2; t++) {
            bf16x8 a;
#pragma unroll
            for (int j = 0; j < 8; j++)
                a[j] = f2bf(wsc[OFF_WKT + (kk * 32 + lg * 8 + j) * 32 + t * 16 + ln]);
            wkf[kk][t] = a;
        }
    bf16x8 wvf[2][4];
#pragma unroll
    for (int kk = 0; kk < 2; kk++)
#pragma unroll
        for (int t = 0; t < 4; t++) {
            bf16x8 a;
#pragma unroll
            for (int j = 0; j < 8; j++)
                a[j] = f2bf(wsc[OFF_WVT + (kk * 32 + lg * 8 + j) * 64 + t * 16 + ln]);
            wvf[kk][t] = a;
        }
    float bkb[2], bvb[4];
#pragma unroll
    for (int t = 0; t < 2; t++) bkb[t] = wsc[OFF_BK + t * 16 + ln];
#pragma unroll
    for (int t = 0; t < 4; t++) bvb[t] = wsc[OFF_BV + t * 16 + ln];

    f32x4 facc[2][4];
#pragma unroll
    for (int t = 0; t < 2; t++)
#pragma unroll
        for (int vt = 0; vt < 4; vt++) facc[t][vt] = (f32x4){0.f, 0.f, 0.f, 0.f};

    const int span0 = bslot * NIT_A;   // chunk units

    f32x4 L[8];
#pragma unroll
    for (int r = 0; r < 8; ++r)
        L[r] = *(const f32x4*)(xn + (size_t)(r * 8 + lc) * HW + span0 * CHUNK_PX + lpx);

#pragma unroll 1
    for (int it = 0; it < NIT_A; ++it) {
        // stage current chunk (compiler waits the gloads feeding ds_write)
#pragma unroll
        for (int r = 0; r < 8; ++r) {
            const int c = r * 8 + lc;
#pragma unroll
            for (int e = 0; e < 4; ++e)
                lds[c * SP + lpx + e] = L[r][e];
        }
        // issue next chunk's loads: in flight across barrier+reads+compute
        if (it + 1 < NIT_A) {
            const int bp = (span0 + it + 1) * CHUNK_PX;
#pragma unroll
            for (int r = 0; r < 8; ++r)
                L[r] = *(const f32x4*)(xn + (size_t)(r * 8 + lc) * HW + bp + lpx);
        }
        LDS_BARRIER();

        // fragment reads for this wave's two 16-px groups
        bf16x8 xag[2][2];
#pragma unroll
        for (int kk = 0; kk < 2; kk++)
#pragma unroll
            for (int j = 0; j < 8; j++) {
                const int c = kk * 32 + lg * 8 + j;
                xag[0][kk][j] = f2bf(lds[c * SP + (w * 32) + ln]);
                xag[1][kk][j] = f2bf(lds[c * SP + (w * 32 + 16) + ln]);
            }
        LDS_BARRIER();   // all reads done -> next iter may overwrite

#pragma unroll
        for (int g = 0; g < 2; ++g) {
            f32x4 dk[2], dv[4];
#pragma unroll
            for (int t = 0; t < 2; t++) dk[t] = (f32x4){bkb[t], bkb[t], bkb[t], bkb[t]};
#pragma unroll
            for (int t = 0; t < 4; t++) dv[t] = (f32x4){bvb[t], bvb[t], bvb[t], bvb[t]};
#pragma unroll
            for (int kk = 0; kk < 2; kk++) {
#pragma unroll
                for (int t = 0; t < 2; t++) dk[t] = MFMA_P(xag[g][kk], wkf[kk][t], dk[t]);
#pragma unroll
                for (int t = 0; t < 4; t++) dv[t] = MFMA_P(xag[g][kk], wvf[kk][t], dv[t]);
            }

            float inv[4];
#pragma unroll
            for (int r = 0; r < 4; r++) {
                float s = dk[0][r] * dk[0][r] + dk[1][r] * dk[1][r];
                s += __shfl_xor(s, 1, 64);
                s += __shfl_xor(s, 2, 64);
                s += __shfl_xor(s, 4, 64);
                s += __shfl_xor(s, 8, 64);
                inv[r] = 1.0f / fmaxf(sqrtf(s), 1e-12f);
            }

            bf16x4 ka[2], vb[4];
#pragma unroll
            for (int t = 0; t < 2; t++)
#pragma unroll
                for (int r = 0; r < 4; r++) ka[t][r] = f2bf(dk[t][r] * inv[r]);
#pragma unroll
            for (int t = 0; t < 4; t++)
#pragma unroll
                for (int r = 0; r < 4; r++) vb[t][r] = f2bf(fmaxf(dv[t][r], 0.0f));

#pragma unroll
            for (int t = 0; t < 2; t++)
#pragma unroll
                for (int vt = 0; vt < 4; vt++)
                    facc[t][vt] = MFMA_O(ka[t], vb[vt], facc[t][vt]);
        }
    }

    // merge 4 waves via lds (reads all done; per-wave regions disjoint)
    float* red = lds;
#pragma unroll
    for (int t = 0; t < 2; t++)
#pragma unroll
        for (int vt = 0; vt < 4; vt++)
#pragma unroll
            for (int r = 0; r < 4; r++)
                red[w * 2048 + (t * 16 + lg * 4 + r) * 64 + vt * 16 + ln] = facc[t][vt][r];
    __syncthreads();
    float* fn = f + n * (QKC * CCH);
    for (int idx = tid; idx < 2048; idx += 256)
        atomicAdd(&fn[idx], red[idx] + red[2048 + idx] + red[4096 + idx] + red[6144 + idx]);
}

// MT[n][i][c] = sum_j Wo'[c][j] * F[n][i][j]
__global__ __launch_bounds__(256) void k2_M(const float* __restrict__ wsc,
                                            float* __restrict__ ws)
{
    const int idx = blockIdx.x * 256 + threadIdx.x;
    if (idx >= NBATCH * QKC * CCH) return;
    const int n = idx / (QKC * CCH);
    const int r = idx % (QKC * CCH);
    const int i = r >> 6, c = r & 63;
    const float* wo = wsc + OFF_WO + c * 64;
    const float* fr = wsc + OFF_F + n * 2048 + i * 64;
    float acc = 0.0f;
#pragma unroll
    for (int j = 0; j < 64; j++) acc += wo[j] * fr[j];
    ws[OFF_MT + idx] = acc;
}

// Pass B: same streaming loader; reverse global block->span mapping (consume
// the spans k1 touched last, still in L3). Stores stay direct (each wave now
// writes a full 128B line per channel across its two groups).
__global__ __launch_bounds__(256) void k3_passB(const float* __restrict__ x,
                                               const float* __restrict__ wsc,
                                               float* __restrict__ out)
{
    __shared__ float xt[64 * SP];
    __shared__ float qt[4][16 * 36];   // per-wave q̂ transpose slab

    const int tid = threadIdx.x;
    const int w = tid >> 6;
    const int lane = tid & 63;
    const int ln = lane & 15;
    const int lg = lane >> 4;
    const int lc = tid >> 5;
    const int lpx = (tid & 31) * 4;

    const int n = NBATCH - 1 - (blockIdx.x / BPN_B);
    const int slot = BPN_B - 1 - (blockIdx.x % BPN_B);
    const float* xn = x + (size_t)n * CCH * HW;
    float* on = out + (size_t)n * CCH * HW;

    bf16x8 wqf[2][2];
#pragma unroll
    for (int kk = 0; kk < 2; kk++)
#pragma unroll
        for (int t = 0; t < 2; t++) {
            bf16x8 a;
#pragma unroll
            for (int j = 0; j < 8; j++)
                a[j] = f2bf(wsc[OFF_WQT + (kk * 32 + lg * 8 + j) * 32 + t * 16 + ln]);
            wqf[kk][t] = a;
        }
    bf16x8 wvf[2][4];
#pragma unroll
    for (int kk = 0; kk < 2; kk++)
#pragma unroll
        for (int t = 0; t < 4; t++) {
            bf16x8 a;
#pragma unroll
            for (int j = 0; j < 8; j++)
                a[j] = f2bf(wsc[OFF_WVT + (kk * 32 + lg * 8 + j) * 64 + t * 16 + ln]);
            wvf[kk][t] = a;
        }
    bf16x8 mtf[4];
#pragma unroll
    for (int t = 0; t < 4; t++) {
        bf16x8 a;
#pragma unroll
        for (int j = 0; j < 8; j++)
            a[j] = f2bf(wsc[OFF_MT + n * 2048 + (lg * 8 + j) * 64 + t * 16 + ln]);
        mtf[t] = a;
    }
    float bqb[2], bvb[4], bob[4];
#pragma unroll
    for (int t = 0; t < 2; t++) bqb[t] = wsc[OFF_BQ + t * 16 + ln];
#pragma unroll
    for (int t = 0; t < 4; t++) bvb[t] = wsc[OFF_BV + t * 16 + ln];
#pragma unroll
    for (int t = 0; t < 4; t++) bob[t] = wsc[OFF_BO + t * 16 + ln];

    const int span0 = slot * NIT_B;

    f32x4 L[8];
    {
        const int bp = (span0 + NIT_B - 1) * CHUNK_PX;   // descending chunk order
#pragma unroll
        for (int r = 0; r < 8; ++r)
            L[r] = *(const f32x4*)(xn + (size_t)(r * 8 + lc) * HW + bp + lpx);
    }

#pragma unroll 1
    for (int it = 0; it < NIT_B; ++it) {
        const int base_px = (span0 + NIT_B - 1 - it) * CHUNK_PX;

#pragma unroll
        for (int r = 0; r < 8; ++r) {
            const int c = r * 8 + lc;
#pragma unroll
            for (int e = 0; e < 4; ++e)
                xt[c * SP + lpx + e] = L[r][e];
        }
        if (it + 1 < NIT_B) {
            const int bp = (span0 + NIT_B - 2 - it) * CHUNK_PX;
#pragma unroll
            for (int r = 0; r < 8; ++r)
                L[r] = *(const f32x4*)(xn + (size_t)(r * 8 + lc) * HW + bp + lpx);
        }
        LDS_BARRIER();

        bf16x8 xag[2][2];
#pragma unroll
        for (int kk = 0; kk < 2; kk++)
#pragma unroll
            for (int j = 0; j < 8; j++) {
                const int c = kk * 32 + lg * 8 + j;
                xag[0][kk][j] = f2bf(xt[c * SP + (w * 32) + ln]);
                xag[1][kk][j] = f2bf(xt[c * SP + (w * 32 + 16) + ln]);
            }
        LDS_BARRIER();

#pragma unroll
        for (int g = 0; g < 2; ++g) {
            const int abs_px = base_px + w * 32 + g * 16;

            f32x4 dq[2], dv0[4];
#pragma unroll
            for (int t = 0; t < 2; t++) dq[t] = (f32x4){bqb[t], bqb[t], bqb[t], bqb[t]};
#pragma unroll
            for (int t = 0; t < 4; t++) dv0[t] = (f32x4){bvb[t], bvb[t], bvb[t], bvb[t]};
#pragma unroll
            for (int kk = 0; kk < 2; kk++) {
#pragma unroll
                for (int t = 0; t < 2; t++) dq[t] = MFMA_P(xag[g][kk], wqf[kk][t], dq[t]);
#pragma unroll
                for (int t = 0; t < 4; t++) dv0[t] = MFMA_P(xag[g][kk], wvf[kk][t], dv0[t]);
            }

            float inv[4];
#pragma unroll
            for (int r = 0; r < 4; r++) {
                float s = dq[0][r] * dq[0][r] + dq[1][r] * dq[1][r];
                s += __shfl_xor(s, 1, 64);
                s += __shfl_xor(s, 2, 64);
                s += __shfl_xor(s, 4, 64);
                s += __shfl_xor(s, 8, 64);
                inv[r] = 1.0f / fmaxf(sqrtf(s), 1e-12f);
            }

            // transpose q̂ through the wave-private slab (wave-local ordering)
#pragma unroll
            for (int t = 0; t < 2; t++)
#pragma unroll
                for (int r = 0; r < 4; r++)
                    qt[w][(lg * 4 + r) * 36 + t * 16 + ln] = dq[t][r] * inv[r];
            const f32x4 qlo = *(const f32x4*)&qt[w][ln * 36 + lg * 8];
            const f32x4 qhi = *(const f32x4*)&qt[w][ln * 36 + lg * 8 + 4];
            bf16x8 aq;
#pragma unroll
            for (int j = 0; j < 4; j++) { aq[j] = f2bf(qlo[j]); aq[4 + j] = f2bf(qhi[j]); }

            f32x4 dy[4];
#pragma unroll
            for (int t = 0; t < 4; t++) dy[t] = (f32x4){bob[t], bob[t], bob[t], bob[t]};
#pragma unroll
            for (int t = 0; t < 4; t++) dy[t] = MFMA_P(aq, mtf[t], dy[t]);

#pragma unroll
            for (int t = 0; t < 4; t++) {
                float* op = on + (size_t)(t * 16 + ln) * HW + abs_px + lg * 4;
                f32x4 o4;
#pragma unroll
                for (int r = 0; r < 4; r++)
                    o4[r] = fmaxf(dy[t][r], 0.0f) + dv0[t][r];
                __builtin_nontemporal_store(o4, (f32x4*)op);
            }
        }
    }
}

extern "C" void kernel_launch(void* const* d_in, const int* in_sizes, int n_in,
                              void* d_out, int out_size, void* d_ws, size_t ws_size,
                              hipStream_t stream)
{
    const float* x    = (const float*)d_in[0];
    const float* Wq   = (const float*)d_in[1];
    const float* bq   = (const float*)d_in[2];
    const float* qg   = (const float*)d_in[3];
    const float* qb   = (const float*)d_in[4];
    const float* qm   = (const float*)d_in[5];
    const float* qv   = (const float*)d_in[6];
    const float* Wk   = (const float*)d_in[7];
    const float* bk   = (const float*)d_in[8];
    const float* kg   = (const float*)d_in[9];
    const float* kb   = (const float*)d_in[10];
    const float* km   = (const float*)d_in[11];
    const float* kvar = (const float*)d_in[12];
    const float* Wv   = (const float*)d_in[13];
    const float* bv   = (const float*)d_in[14];
    const float* vg   = (const float*)d_in[15];
    const float* vb   = (const float*)d_in[16];
    const float* vm   = (const float*)d_in[17];
    const float* vvar = (const float*)d_in[18];
    const float* Wo   = (const float*)d_in[19];
    const float* bo   = (const float*)d_in[20];
    const float* og   = (const float*)d_in[21];
    const float* ob   = (const float*)d_in[22];
    const float* om   = (const float*)d_in[23];
    const float* ovar = (const float*)d_in[24];

    float* ws  = (float*)d_ws;
    float* out = (float*)d_out;

    k0_fold<<<177, 256, 0, stream>>>(Wq, bq, qg, qb, qm, qv,
                                     Wk, bk, kg, kb, km, kvar,
                                     Wv, bv, vg, vb, vm, vvar,
                                     Wo, bo, og, ob, om, ovar, ws);

    k1_passA<<<NBATCH * BPN_A, 256, 0, stream>>>(x, (const float*)ws, ws + OFF_F);

    k2_M<<<128, 256, 0, stream>>>((const float*)ws, ws);

    k3_passB<<<NBATCH * BPN_B, 256, 0, stream>>>(x, (const float*)ws, out);
}

// Round 11
// 186.377 us; speedup vs baseline: 1.1994x; 1.1994x over previous
//
#include <hip/hip_runtime.h>

#define HW 65536
#define NBATCH 16
#define CCH 64
#define QKC 32

// workspace layout (float offsets)
#define OFF_WQT 0        // [64][32]  WqT folded (c-major rows of 32)
#define OFF_BQ  2048     // [32]
#define OFF_WKT 2080     // [64][32]
#define OFF_BK  4128     // [32]
#define OFF_WVT 4160     // [64][64]
#define OFF_BV  8256     // [64]
#define OFF_WO  8320     // [64][64]  row-major [c][j]
#define OFF_BO  12416    // [64]
#define OFF_F   12544    // [16][32][64]
#define OFF_MT  45312    // [16][32][64]

#define BPN_A 32
#define BPN_B 32
#define NIT_A (HW / 128 / BPN_A)   // 16 chunks of 128 px (contiguous 2048-px span)
#define NIT_B (HW / 64 / BPN_B)    // 32 chunks of 64 px  (contiguous 2048-px span)

typedef __attribute__((ext_vector_type(2))) float f32x2;
typedef __attribute__((ext_vector_type(4))) float f32x4;
typedef __attribute__((ext_vector_type(8))) short bf16x8;
typedef __attribute__((ext_vector_type(4))) short bf16x4;

#define MFMA_P(a, b, c) __builtin_amdgcn_mfma_f32_16x16x32_bf16(a, b, c, 0, 0, 0)
#define MFMA_O(a, b, c) __builtin_amdgcn_mfma_f32_16x16x16bf16_1k(a, b, c, 0, 0, 0)

// float -> bf16 via hardware cvt (m240: plain cast compiles to the HW instr)
__device__ __forceinline__ short f2bf(float f) {
    __bf16 h = (__bf16)f;
    return __builtin_bit_cast(short, h);
}

__global__ __launch_bounds__(256) void k0_fold(
    const float* __restrict__ Wq, const float* __restrict__ bq,
    const float* __restrict__ qg, const float* __restrict__ qb,
    const float* __restrict__ qm, const float* __restrict__ qv,
    const float* __restrict__ Wk, const float* __restrict__ bk,
    const float* __restrict__ kg, const float* __restrict__ kb,
    const float* __restrict__ km, const float* __restrict__ kvar,
    const float* __restrict__ Wv, const float* __restrict__ bv,
    const float* __restrict__ vg, const float* __restrict__ vb,
    const float* __restrict__ vm, const float* __restrict__ vvar,
    const float* __restrict__ Wo, const float* __restrict__ bo,
    const float* __restrict__ og, const float* __restrict__ ob,
    const float* __restrict__ om, const float* __restrict__ ovar,
    float* __restrict__ ws)
{
    const int idx = blockIdx.x * 256 + threadIdx.x;
    if (idx < 2048) {                       // WqT[c][i]
        const int c = idx >> 5, i = idx & 31;
        const float s = qg[i] * rsqrtf(qv[i] + 1e-5f);
        ws[OFF_WQT + idx] = Wq[i * 64 + c] * s;
    } else if (idx < 2080) {
        const int i = idx - 2048;
        const float s = qg[i] * rsqrtf(qv[i] + 1e-5f);
        ws[OFF_BQ + i] = bq[i] * s + qb[i] - qm[i] * s;
    } else if (idx < 4128) {                // WkT[c][i]
        const int t = idx - 2080;
        const int c = t >> 5, i = t & 31;
        const float s = kg[i] * rsqrtf(kvar[i] + 1e-5f);
        ws[OFF_WKT + t] = Wk[i * 64 + c] * s;
    } else if (idx < 4160) {
        const int i = idx - 4128;
        const float s = kg[i] * rsqrtf(kvar[i] + 1e-5f);
        ws[OFF_BK + i] = bk[i] * s + kb[i] - km[i] * s;
    } else if (idx < 8256) {                // WvT[c][o]
        const int t = idx - 4160;
        const int c = t >> 6, o = t & 63;
        const float s = vg[o] * rsqrtf(vvar[o] + 1e-5f);
        ws[OFF_WVT + t] = Wv[o * 64 + c] * s;
    } else if (idx < 8320) {
        const int o = idx - 8256;
        const float s = vg[o] * rsqrtf(vvar[o] + 1e-5f);
        ws[OFF_BV + o] = bv[o] * s + vb[o] - vm[o] * s;
    } else if (idx < 12416) {               // Wo'[c][j]
        const int t = idx - 8320;
        const int c = t >> 6, j = t & 63;
        const float s = og[c] * rsqrtf(ovar[c] + 1e-5f);
        ws[OFF_WO + t] = Wo[c * 64 + j] * s;
    } else if (idx < 12480) {
        const int c = idx - 12416;
        const float s = og[c] * rsqrtf(ovar[c] + 1e-5f);
        ws[OFF_BO + c] = bo[c] * s + ob[c] - om[c] * s;
    } else if (idx < 12480 + 32768) {       // zero F (must happen every launch)
        ws[OFF_F + (idx - 12480)] = 0.0f;
    }
}

// Pass A (MFMA): f = sum_px k̂·v̂^T is permutation-invariant over pixels, so
// pixel-slot m maps to pixel base+2m+e (e = 0,1): lane ln loads one f32x2
// per channel covering BOTH groups -> 128B load segments (2x round 9), zero
// shuffles, zero LDS. Contiguous 2048-px span per block; x double-buffered.
__global__ __launch_bounds__(256) void k1_passA(const float* __restrict__ x,
                                                const float* __restrict__ wsc,
                                                float* __restrict__ f)
{
    __shared__ float red[4 * 2048];

    const int tid = threadIdx.x;
    const int w = tid >> 6;
    const int lane = tid & 63;
    const int ln = lane & 15;
    const int lg = lane >> 4;

    const int n = blockIdx.x / BPN_A;
    const int bslot = blockIdx.x % BPN_A;
    const float* xn = x + (size_t)n * CCH * HW;

    bf16x8 wkf[2][2];
#pragma unroll
    for (int kk = 0; kk < 2; kk++)
#pragma unroll
        for (int t = 0; t < 2; t++) {
            bf16x8 a;
#pragma unroll
            for (int j = 0; j < 8; j++)
                a[j] = f2bf(wsc[OFF_WKT + (kk * 32 + lg * 8 + j) * 32 + t * 16 + ln]);
            wkf[kk][t] = a;
        }
    bf16x8 wvf[2][4];
#pragma unroll
    for (int kk = 0; kk < 2; kk++)
#pragma unroll
        for (int t = 0; t < 4; t++) {
            bf16x8 a;
#pragma unroll
            for (int j = 0; j < 8; j++)
                a[j] = f2bf(wsc[OFF_WVT + (kk * 32 + lg * 8 + j) * 64 + t * 16 + ln]);
            wvf[kk][t] = a;
        }
    float bkb[2], bvb[4];
#pragma unroll
    for (int t = 0; t < 2; t++) bkb[t] = wsc[OFF_BK + t * 16 + ln];
#pragma unroll
    for (int t = 0; t < 4; t++) bvb[t] = wsc[OFF_BV + t * 16 + ln];

    f32x4 facc[2][4];
#pragma unroll
    for (int t = 0; t < 2; t++)
#pragma unroll
        for (int vt = 0; vt < 4; vt++) facc[t][vt] = (f32x4){0.f, 0.f, 0.f, 0.f};

    const int span0 = bslot * NIT_A;   // 128-px chunk units

    f32x2 xf[16];
    {
        const int base = span0 * 128 + w * 32;
#pragma unroll
        for (int kk = 0; kk < 2; kk++)
#pragma unroll
            for (int j = 0; j < 8; j++)
                xf[kk * 8 + j] = *(const f32x2*)(xn + (size_t)(kk * 32 + lg * 8 + j) * HW
                                                 + base + 2 * ln);
    }

#pragma unroll 1
    for (int it = 0; it < NIT_A; ++it) {
        f32x2 xf2[16];
        if (it + 1 < NIT_A) {
            const int b2 = (span0 + it + 1) * 128 + w * 32;
#pragma unroll
            for (int kk = 0; kk < 2; kk++)
#pragma unroll
                for (int j = 0; j < 8; j++)
                    xf2[kk * 8 + j] = *(const f32x2*)(xn + (size_t)(kk * 32 + lg * 8 + j) * HW
                                                      + b2 + 2 * ln);
        }

        // both groups' fragments from the same registers (e = px parity)
        bf16x8 xag[2][2];
#pragma unroll
        for (int e = 0; e < 2; e++)
#pragma unroll
            for (int kk = 0; kk < 2; kk++)
#pragma unroll
                for (int j = 0; j < 8; j++)
                    xag[e][kk][j] = f2bf(xf[kk * 8 + j][e]);

#pragma unroll
        for (int g = 0; g < 2; ++g) {
            f32x4 dk[2], dv[4];
#pragma unroll
            for (int t = 0; t < 2; t++) dk[t] = (f32x4){bkb[t], bkb[t], bkb[t], bkb[t]};
#pragma unroll
            for (int t = 0; t < 4; t++) dv[t] = (f32x4){bvb[t], bvb[t], bvb[t], bvb[t]};
#pragma unroll
            for (int kk = 0; kk < 2; kk++) {
#pragma unroll
                for (int t = 0; t < 2; t++) dk[t] = MFMA_P(xag[g][kk], wkf[kk][t], dk[t]);
#pragma unroll
                for (int t = 0; t < 4; t++) dv[t] = MFMA_P(xag[g][kk], wvf[kk][t], dv[t]);
            }

            float inv[4];
#pragma unroll
            for (int r = 0; r < 4; r++) {
                float s = dk[0][r] * dk[0][r] + dk[1][r] * dk[1][r];
                s += __shfl_xor(s, 1, 64);
                s += __shfl_xor(s, 2, 64);
                s += __shfl_xor(s, 4, 64);
                s += __shfl_xor(s, 8, 64);
                inv[r] = 1.0f / fmaxf(sqrtf(s), 1e-12f);
            }

            bf16x4 ka[2], vb[4];
#pragma unroll
            for (int t = 0; t < 2; t++)
#pragma unroll
                for (int r = 0; r < 4; r++) ka[t][r] = f2bf(dk[t][r] * inv[r]);
#pragma unroll
            for (int t = 0; t < 4; t++)
#pragma unroll
                for (int r = 0; r < 4; r++) vb[t][r] = f2bf(fmaxf(dv[t][r], 0.0f));

#pragma unroll
            for (int t = 0; t < 2; t++)
#pragma unroll
                for (int vt = 0; vt < 4; vt++)
                    facc[t][vt] = MFMA_O(ka[t], vb[vt], facc[t][vt]);
        }

        if (it + 1 < NIT_A) {
#pragma unroll
            for (int i = 0; i < 16; i++) xf[i] = xf2[i];
        }
    }

#pragma unroll
    for (int t = 0; t < 2; t++)
#pragma unroll
        for (int vt = 0; vt < 4; vt++)
#pragma unroll
            for (int r = 0; r < 4; r++)
                red[w * 2048 + (t * 16 + lg * 4 + r) * 64 + vt * 16 + ln] = facc[t][vt][r];
    __syncthreads();
    float* fn = f + n * (QKC * CCH);
    for (int idx = tid; idx < 2048; idx += 256)
        atomicAdd(&fn[idx], red[idx] + red[2048 + idx] + red[4096 + idx] + red[6144 + idx]);
}

// MT[n][i][c] = sum_j Wo'[c][j] * F[n][i][j]
__global__ __launch_bounds__(256) void k2_M(const float* __restrict__ wsc,
                                            float* __restrict__ ws)
{
    const int idx = blockIdx.x * 256 + threadIdx.x;
    if (idx >= NBATCH * QKC * CCH) return;
    const int n = idx / (QKC * CCH);
    const int r = idx % (QKC * CCH);
    const int i = r >> 6, c = r & 63;
    const float* wo = wsc + OFF_WO + c * 64;
    const float* fr = wsc + OFF_F + n * 2048 + i * 64;
    float acc = 0.0f;
#pragma unroll
    for (int j = 0; j < 64; j++) acc += wo[j] * fr[j];
    ws[OFF_MT + idx] = acc;
}

// Pass B (MFMA): round-9 structure (stores need the consecutive-px mapping).
// Contiguous 2048-px span per block; reverse global block->span mapping so
// the earliest k3 blocks consume the spans k1 touched last (L3-hot).
__global__ __launch_bounds__(256) void k3_passB(const float* __restrict__ x,
                                               const float* __restrict__ wsc,
                                               float* __restrict__ out)
{
    __shared__ float qt[4][16 * 36];   // per-wave q̂ transpose buffer (pad 36)

    const int tid = threadIdx.x;
    const int w = tid >> 6;
    const int lane = tid & 63;
    const int ln = lane & 15;
    const int lg = lane >> 4;

    const int n = NBATCH - 1 - (blockIdx.x / BPN_B);
    const int slot = BPN_B - 1 - (blockIdx.x % BPN_B);
    const float* xn = x + (size_t)n * CCH * HW;
    float* on = out + (size_t)n * CCH * HW;

    bf16x8 wqf[2][2];
#pragma unroll
    for (int kk = 0; kk < 2; kk++)
#pragma unroll
        for (int t = 0; t < 2; t++) {
            bf16x8 a;
#pragma unroll
            for (int j = 0; j < 8; j++)
                a[j] = f2bf(wsc[OFF_WQT + (kk * 32 + lg * 8 + j) * 32 + t * 16 + ln]);
            wqf[kk][t] = a;
        }
    bf16x8 wvf[2][4];
#pragma unroll
    for (int kk = 0; kk < 2; kk++)
#pragma unroll
        for (int t = 0; t < 4; t++) {
            bf16x8 a;
#pragma unroll
            for (int j = 0; j < 8; j++)
                a[j] = f2bf(wsc[OFF_WVT + (kk * 32 + lg * 8 + j) * 64 + t * 16 + ln]);
            wvf[kk][t] = a;
        }
    bf16x8 mtf[4];
#pragma unroll
    for (int t = 0; t < 4; t++) {
        bf16x8 a;
#pragma unroll
        for (int j = 0; j < 8; j++)
            a[j] = f2bf(wsc[OFF_MT + n * 2048 + (lg * 8 + j) * 64 + t * 16 + ln]);
        mtf[t] = a;
    }
    float bqb[2], bvb[4], bob[4];
#pragma unroll
    for (int t = 0; t < 2; t++) bqb[t] = wsc[OFF_BQ + t * 16 + ln];
#pragma unroll
    for (int t = 0; t < 4; t++) bvb[t] = wsc[OFF_BV + t * 16 + ln];
#pragma unroll
    for (int t = 0; t < 4; t++) bob[t] = wsc[OFF_BO + t * 16 + ln];

    const int span0 = slot * NIT_B;   // 64-px chunk units; descending order

    float xf[16];
    {
        const int sbase = (span0 + NIT_B - 1) * 64 + w * 16;
#pragma unroll
        for (int kk = 0; kk < 2; kk++) {
            const float* xp = xn + (size_t)(kk * 32 + lg * 8) * HW + sbase + ln;
#pragma unroll
            for (int j = 0; j < 8; j++) xf[kk * 8 + j] = xp[j * HW];
        }
    }

#pragma unroll 1
    for (int it = 0; it < NIT_B; ++it) {
        const int sbase = (span0 + NIT_B - 1 - it) * 64 + w * 16;

        float xf2[16];
        if (it + 1 < NIT_B) {
            const int sb2 = (span0 + NIT_B - 2 - it) * 64 + w * 16;
#pragma unroll
            for (int kk = 0; kk < 2; kk++) {
                const float* xp = xn + (size_t)(kk * 32 + lg * 8) * HW + sb2 + ln;
#pragma unroll
                for (int j = 0; j < 8; j++) xf2[kk * 8 + j] = xp[j * HW];
            }
        }

        bf16x8 xa[2];
#pragma unroll
        for (int kk = 0; kk < 2; kk++)
#pragma unroll
            for (int j = 0; j < 8; j++) xa[kk][j] = f2bf(xf[kk * 8 + j]);

        f32x4 dq[2], dv0[4];
#pragma unroll
        for (int t = 0; t < 2; t++) dq[t] = (f32x4){bqb[t], bqb[t], bqb[t], bqb[t]};
#pragma unroll
        for (int t = 0; t < 4; t++) dv0[t] = (f32x4){bvb[t], bvb[t], bvb[t], bvb[t]};
#pragma unroll
        for (int kk = 0; kk < 2; kk++) {
#pragma unroll
            for (int t = 0; t < 2; t++) dq[t] = MFMA_P(xa[kk], wqf[kk][t], dq[t]);
#pragma unroll
            for (int t = 0; t < 4; t++) dv0[t] = MFMA_P(xa[kk], wvf[kk][t], dv0[t]);
        }

        float inv[4];
#pragma unroll
        for (int r = 0; r < 4; r++) {
            float s = dq[0][r] * dq[0][r] + dq[1][r] * dq[1][r];
            s += __shfl_xor(s, 1, 64);
            s += __shfl_xor(s, 2, 64);
            s += __shfl_xor(s, 4, 64);
            s += __shfl_xor(s, 8, 64);
            inv[r] = 1.0f / fmaxf(sqrtf(s), 1e-12f);
        }

        // transpose q̂ through the wave-private LDS slab (wave-local ordering)
#pragma unroll
        for (int t = 0; t < 2; t++)
#pragma unroll
            for (int r = 0; r < 4; r++)
                qt[w][(lg * 4 + r) * 36 + t * 16 + ln] = dq[t][r] * inv[r];
        const f32x4 qlo = *(const f32x4*)&qt[w][ln * 36 + lg * 8];
        const f32x4 qhi = *(const f32x4*)&qt[w][ln * 36 + lg * 8 + 4];
        bf16x8 aq;
#pragma unroll
        for (int j = 0; j < 4; j++) { aq[j] = f2bf(qlo[j]); aq[4 + j] = f2bf(qhi[j]); }

        f32x4 dy[4];
#pragma unroll
        for (int t = 0; t < 4; t++) dy[t] = (f32x4){bob[t], bob[t], bob[t], bob[t]};
#pragma unroll
        for (int t = 0; t < 4; t++) dy[t] = MFMA_P(aq, mtf[t], dy[t]);

        // out[och][px] = relu(y) + v0  (nontemporal: don't evict x from L3)
#pragma unroll
        for (int t = 0; t < 4; t++) {
            float* op = on + (size_t)(t * 16 + ln) * HW + sbase + lg * 4;
            f32x4 o4;
#pragma unroll
            for (int r = 0; r < 4; r++)
                o4[r] = fmaxf(dy[t][r], 0.0f) + dv0[t][r];
            __builtin_nontemporal_store(o4, (f32x4*)op);
        }

        if (it + 1 < NIT_B) {
#pragma unroll
            for (int i = 0; i < 16; i++) xf[i] = xf2[i];
        }
    }
}

extern "C" void kernel_launch(void* const* d_in, const int* in_sizes, int n_in,
                              void* d_out, int out_size, void* d_ws, size_t ws_size,
                              hipStream_t stream)
{
    const float* x    = (const float*)d_in[0];
    const float* Wq   = (const float*)d_in[1];
    const float* bq   = (const float*)d_in[2];
    const float* qg   = (const float*)d_in[3];
    const float* qb   = (const float*)d_in[4];
    const float* qm   = (const float*)d_in[5];
    const float* qv   = (const float*)d_in[6];
    const float* Wk   = (const float*)d_in[7];
    const float* bk   = (const float*)d_in[8];
    const float* kg   = (const float*)d_in[9];
    const float* kb   = (const float*)d_in[10];
    const float* km   = (const float*)d_in[11];
    const float* kvar = (const float*)d_in[12];
    const float* Wv   = (const float*)d_in[13];
    const float* bv   = (const float*)d_in[14];
    const float* vg   = (const float*)d_in[15];
    const float* vb   = (const float*)d_in[16];
    const float* vm   = (const float*)d_in[17];
    const float* vvar = (const float*)d_in[18];
    const float* Wo   = (const float*)d_in[19];
    const float* bo   = (const float*)d_in[20];
    const float* og   = (const float*)d_in[21];
    const float* ob   = (const float*)d_in[22];
    const float* om   = (const float*)d_in[23];
    const float* ovar = (const float*)d_in[24];

    float* ws  = (float*)d_ws;
    float* out = (float*)d_out;

    k0_fold<<<177, 256, 0, stream>>>(Wq, bq, qg, qb, qm, qv,
                                     Wk, bk, kg, kb, km, kvar,
                                     Wv, bv, vg, vb, vm, vvar,
                                     Wo, bo, og, ob, om, ovar, ws);

    k1_passA<<<NBATCH * BPN_A, 256, 0, stream>>>(x, (const float*)ws, ws + OFF_F);

    k2_M<<<128, 256, 0, stream>>>((const float*)ws, ws);

    k3_passB<<<NBATCH * BPN_B, 256, 0, stream>>>(x, (const float*)ws, out);
}